// Round 1
// baseline (339.573 us; speedup 1.0000x reference)
//
#include <hip/hip_runtime.h>

// Problem constants (fixed shapes from setup_inputs)
#define BATCH 2
#define HH 64
#define WW 64
#define CC 128
#define OHH 32
#define OWW 32
#define NPOOL (OHH * OWW * CC)            // 131072
#define NOUT 32
#define NIN (HH * WW * CC)                // 524288
#define WZERO ((size_t)BATCH * NIN * NOUT)  // 33554432 floats per w_zero output

// Flat offsets into d_out (floats), concatenated in return order:
// w_zero(33554432) | b_out_u_(64) | w_zero(33554432) | b_out_l_(64)
#define OFF_BU (WZERO)
#define OFF_BL (2 * WZERO + (size_t)BATCH * NOUT)

#define CHUNKS 128                 // blocks per batch element in reduce
#define PPC (NPOOL / CHUNKS)       // 1024 pooled positions per block

// Computes b_u = maxpool2x2(u_c), b_l = maxpool2x2(l_c) into workspace
// (float4 over channel dim), and seeds the output bias slots with
// b_out_u / b_out_l (runs after the memset on the same stream).
__global__ void pool_kernel(const float4* __restrict__ u_c,
                            const float4* __restrict__ l_c,
                            float4* __restrict__ bu,
                            float4* __restrict__ bl,
                            const float* __restrict__ b_out_u,
                            const float* __restrict__ b_out_l,
                            float* __restrict__ out) {
    int tid = blockIdx.x * blockDim.x + threadIdx.x;   // 65536 threads total
    int c4 = tid & 31;              // 128/4 channel quads
    int ow = (tid >> 5) & 31;
    int oh = (tid >> 10) & 31;
    int b  = tid >> 15;

    // float4-unit addressing: ((b*H + h)*W + w)*32 + c4
    int base = ((b * HH + 2 * oh) * WW + 2 * ow) * (CC / 4) + c4;
    const int colstep = CC / 4;          // +1 in w
    const int rowstep = WW * (CC / 4);   // +1 in h

    {
        float4 a0 = u_c[base];
        float4 a1 = u_c[base + colstep];
        float4 a2 = u_c[base + rowstep];
        float4 a3 = u_c[base + rowstep + colstep];
        float4 m;
        m.x = fmaxf(fmaxf(a0.x, a1.x), fmaxf(a2.x, a3.x));
        m.y = fmaxf(fmaxf(a0.y, a1.y), fmaxf(a2.y, a3.y));
        m.z = fmaxf(fmaxf(a0.z, a1.z), fmaxf(a2.z, a3.z));
        m.w = fmaxf(fmaxf(a0.w, a1.w), fmaxf(a2.w, a3.w));
        bu[tid] = m;
    }
    {
        float4 a0 = l_c[base];
        float4 a1 = l_c[base + colstep];
        float4 a2 = l_c[base + rowstep];
        float4 a3 = l_c[base + rowstep + colstep];
        float4 m;
        m.x = fmaxf(fmaxf(a0.x, a1.x), fmaxf(a2.x, a3.x));
        m.y = fmaxf(fmaxf(a0.y, a1.y), fmaxf(a2.y, a3.y));
        m.z = fmaxf(fmaxf(a0.z, a1.z), fmaxf(a2.z, a3.z));
        m.w = fmaxf(fmaxf(a0.w, a1.w), fmaxf(a2.w, a3.w));
        bl[tid] = m;
    }

    // Seed bias slots (zeroed by the preceding memset) with b_out_u / b_out_l.
    if (blockIdx.x == 0 && threadIdx.x < BATCH * NOUT) {
        out[OFF_BU + threadIdx.x] = b_out_u[threadIdx.x];
        out[OFF_BL + threadIdx.x] = b_out_l[threadIdx.x];
    }
}

// Folds backward weights into constant biases:
//   b_out_u_ += sum_p max(w_u,0)*b_u[p] + min(w_u,0)*b_l[p]
//   b_out_l_ += sum_p max(w_l,0)*b_l[p] + min(w_l,0)*b_u[p]
// Thread layout: o-quad fastest (og = t&7 -> 4 consecutive n_out cols via
// float4), pl = t>>3 strides pooled positions -> fully coalesced w reads.
__global__ void reduce_kernel(const float4* __restrict__ wu,
                              const float4* __restrict__ wl,
                              const float* __restrict__ bu,
                              const float* __restrict__ bl,
                              float* __restrict__ out) {
    int b = blockIdx.x / CHUNKS;
    int chunk = blockIdx.x % CHUNKS;
    int t = threadIdx.x;
    int og = t & 7;    // which float4 of the 32 outputs
    int pl = t >> 3;   // 0..31

    float4 au = make_float4(0.f, 0.f, 0.f, 0.f);
    float4 al = make_float4(0.f, 0.f, 0.f, 0.f);

    const float* bub = bu + b * NPOOL;
    const float* blb = bl + b * NPOOL;
    int p0 = chunk * PPC;

    for (int p = p0 + pl; p < p0 + PPC; p += 32) {
        float vbu = bub[p];
        float vbl = blb[p];
        size_t widx = ((size_t)b * NPOOL + p) * (NOUT / 4) + og;
        float4 u4 = wu[widx];
        float4 l4 = wl[widx];
        au.x += fmaxf(u4.x, 0.f) * vbu + fminf(u4.x, 0.f) * vbl;
        au.y += fmaxf(u4.y, 0.f) * vbu + fminf(u4.y, 0.f) * vbl;
        au.z += fmaxf(u4.z, 0.f) * vbu + fminf(u4.z, 0.f) * vbl;
        au.w += fmaxf(u4.w, 0.f) * vbu + fminf(u4.w, 0.f) * vbl;
        al.x += fmaxf(l4.x, 0.f) * vbl + fminf(l4.x, 0.f) * vbu;
        al.y += fmaxf(l4.y, 0.f) * vbl + fminf(l4.y, 0.f) * vbu;
        al.z += fmaxf(l4.z, 0.f) * vbl + fminf(l4.z, 0.f) * vbu;
        al.w += fmaxf(l4.w, 0.f) * vbl + fminf(l4.w, 0.f) * vbu;
    }

    __shared__ float4 su[256];
    __shared__ float4 sl[256];
    su[t] = au;
    sl[t] = al;
    __syncthreads();

    // Tree reduce across pl (strides are multiples of 8, preserving og)
    for (int s = 128; s >= 8; s >>= 1) {
        if (t < s) {
            float4 xu = su[t + s];
            su[t].x += xu.x; su[t].y += xu.y; su[t].z += xu.z; su[t].w += xu.w;
            float4 xl = sl[t + s];
            sl[t].x += xl.x; sl[t].y += xl.y; sl[t].z += xl.z; sl[t].w += xl.w;
        }
        __syncthreads();
    }

    if (t < 8) {
        float4 ru = su[t];
        float4 rl = sl[t];
        float* ou = out + OFF_BU + (size_t)b * NOUT + t * 4;
        float* ol = out + OFF_BL + (size_t)b * NOUT + t * 4;
        atomicAdd(&ou[0], ru.x);
        atomicAdd(&ou[1], ru.y);
        atomicAdd(&ou[2], ru.z);
        atomicAdd(&ou[3], ru.w);
        atomicAdd(&ol[0], rl.x);
        atomicAdd(&ol[1], rl.y);
        atomicAdd(&ol[2], rl.z);
        atomicAdd(&ol[3], rl.w);
    }
}

extern "C" void kernel_launch(void* const* d_in, const int* in_sizes, int n_in,
                              void* d_out, int out_size, void* d_ws, size_t ws_size,
                              hipStream_t stream) {
    // setup_inputs order: y, x_0, u_c, l_c, w_out_u, b_out_u, w_out_l, b_out_l
    const float* u_c     = (const float*)d_in[2];
    const float* l_c     = (const float*)d_in[3];
    const float* w_out_u = (const float*)d_in[4];
    const float* b_out_u = (const float*)d_in[5];
    const float* w_out_l = (const float*)d_in[6];
    const float* b_out_l = (const float*)d_in[7];
    float* out = (float*)d_out;

    float* ws_bu = (float*)d_ws;                 // BATCH*NPOOL floats (1 MB)
    float* ws_bl = ws_bu + (size_t)BATCH * NPOOL;

    // 1) Zero the entire output (the two w_zero tensors ARE the output bulk).
    hipMemsetAsync(d_out, 0, (size_t)out_size * sizeof(float), stream);

    // 2) Maxpool u_c/l_c into workspace + seed bias slots.
    pool_kernel<<<256, 256, 0, stream>>>(
        (const float4*)u_c, (const float4*)l_c,
        (float4*)ws_bu, (float4*)ws_bl,
        b_out_u, b_out_l, out);

    // 3) Fold weights into biases.
    reduce_kernel<<<BATCH * CHUNKS, 256, 0, stream>>>(
        (const float4*)w_out_u, (const float4*)w_out_l,
        ws_bu, ws_bl, out);
}